// Round 1
// baseline (290.088 us; speedup 1.0000x reference)
//
#include <hip/hip_runtime.h>
#include <hip/hip_bf16.h>

// Sizes fixed by the problem
constexpr int Bb = 32;
constexpr int Ll = 2048;
constexpr int Mm = 512;
constexpr int Hh = 512;
constexpr int Aa = 256;

typedef __attribute__((ext_vector_type(4))) float f32x4;
typedef __attribute__((ext_vector_type(8))) short short8;
typedef __attribute__((ext_vector_type(4))) unsigned short ushort4v;

__device__ __forceinline__ unsigned short f2bf(float f) {
    __hip_bfloat16 h = __float2bfloat16(f);   // RNE
    return *reinterpret_cast<unsigned short*>(&h);
}

// ---------------- k0: W1[:, :512] -> bf16 (row-major A x M) ----------------
__global__ void k_convert_w1m(const float* __restrict__ W1,
                              unsigned short* __restrict__ W1mb) {
    int i = blockIdx.x * 256 + threadIdx.x;        // 32768 threads, 4 floats each
    int a  = i >> 7;                               // 128 float4 per row
    int mq = (i & 127) << 2;
    f32x4 v = *reinterpret_cast<const f32x4*>(W1 + (size_t)a * (Mm + Hh) + mq);
    ushort4v o;
    o[0] = f2bf(v[0]); o[1] = f2bf(v[1]); o[2] = f2bf(v[2]); o[3] = f2bf(v[3]);
    *reinterpret_cast<ushort4v*>(W1mb + (size_t)a * Mm + mq) = o;
}

// ---------------- k1: hb[b][a] = sum_h hidden[b,h]*W1[a,512+h] + b1[a] -----
__global__ void k_hb(const float* __restrict__ hidden, const float* __restrict__ W1,
                     const float* __restrict__ b1, float* __restrict__ hb) {
    int b  = blockIdx.x >> 2;
    int hc = blockIdx.x & 3;                       // 4 chunks of 128 h
    int a  = threadIdx.x;                          // 256 threads
    __shared__ float sh[128];
    if (threadIdx.x < 128) sh[threadIdx.x] = hidden[b * Hh + hc * 128 + threadIdx.x];
    __syncthreads();
    const float* wrow = W1 + (size_t)a * (Mm + Hh) + Mm + hc * 128;
    float acc = (hc == 0) ? b1[a] : 0.f;
    #pragma unroll 8
    for (int h = 0; h < 128; h += 4) {
        f32x4 w = *reinterpret_cast<const f32x4*>(wrow + h);
        acc += w[0] * sh[h] + w[1] * sh[h + 1] + w[2] * sh[h + 2] + w[3] * sh[h + 3];
    }
    atomicAdd(&hb[b * Aa + a], acc);
}

// ---------------- k2: fused score GEMM ------------------------------------
// score[b,l] = sum_a tanh( mem[b,l,:].W1m[a,:] + hb[b,a] ) * W2[a]
// Grid 512 blocks x 256 thr. Block = 4 waves x 32 rows = 128 rows of (b,l).
// Wave: 2 row-tiles (16x16) x 16 col-tiles, K = 512 in 16 steps of 32.
__launch_bounds__(256, 2)
__global__ void k_score(const float* __restrict__ mem,
                        const unsigned short* __restrict__ W1mb,
                        const float* __restrict__ hb, const float* __restrict__ W2,
                        float* __restrict__ score) {
    const int wave = threadIdx.x >> 6;
    const int lane = threadIdx.x & 63;
    const int g = lane >> 4;                       // k-group 0..3
    const int r = lane & 15;                       // own-dim index
    const int rowbase = blockIdx.x * 128 + wave * 32;
    const int b = rowbase >> 11;                   // 2048 rows per batch

    f32x4 acc[2][16];
    #pragma unroll
    for (int rt = 0; rt < 2; rt++)
        #pragma unroll
        for (int ct = 0; ct < 16; ct++)
            acc[rt][ct] = (f32x4){0.f, 0.f, 0.f, 0.f};

    const float* ap0 = mem + (size_t)(rowbase + r) * Mm + g * 8;
    const float* ap1 = ap0 + (size_t)16 * Mm;
    const unsigned short* bp0 = W1mb + (size_t)r * Mm + g * 8;

    for (int ks = 0; ks < 16; ++ks) {
        const int ko = ks * 32;
        // A fragments: fp32 from HBM, convert in-register to bf16
        short8 af0, af1;
        {
            f32x4 lo = *reinterpret_cast<const f32x4*>(ap0 + ko);
            f32x4 hi = *reinterpret_cast<const f32x4*>(ap0 + ko + 4);
            af0[0] = (short)f2bf(lo[0]); af0[1] = (short)f2bf(lo[1]);
            af0[2] = (short)f2bf(lo[2]); af0[3] = (short)f2bf(lo[3]);
            af0[4] = (short)f2bf(hi[0]); af0[5] = (short)f2bf(hi[1]);
            af0[6] = (short)f2bf(hi[2]); af0[7] = (short)f2bf(hi[3]);
        }
        {
            f32x4 lo = *reinterpret_cast<const f32x4*>(ap1 + ko);
            f32x4 hi = *reinterpret_cast<const f32x4*>(ap1 + ko + 4);
            af1[0] = (short)f2bf(lo[0]); af1[1] = (short)f2bf(lo[1]);
            af1[2] = (short)f2bf(lo[2]); af1[3] = (short)f2bf(lo[3]);
            af1[4] = (short)f2bf(hi[0]); af1[5] = (short)f2bf(hi[1]);
            af1[6] = (short)f2bf(hi[2]); af1[7] = (short)f2bf(hi[3]);
        }
        // B fragments: bf16 W1m (N x K row-major = B^T pattern), L2-resident.
        // Two halves of 8 col-tiles to bound register pressure.
        #pragma unroll
        for (int half = 0; half < 2; ++half) {
            short8 bf[8];
            #pragma unroll
            for (int j = 0; j < 8; ++j) {
                int ct = half * 8 + j;
                bf[j] = *reinterpret_cast<const short8*>(bp0 + (size_t)ct * 16 * Mm + ko);
            }
            #pragma unroll
            for (int j = 0; j < 8; ++j) {
                int ct = half * 8 + j;
                acc[0][ct] = __builtin_amdgcn_mfma_f32_16x16x32_bf16(af0, bf[j], acc[0][ct], 0, 0, 0);
                acc[1][ct] = __builtin_amdgcn_mfma_f32_16x16x32_bf16(af1, bf[j], acc[1][ct], 0, 0, 0);
            }
        }
    }

    // Epilogue: C/D layout col=lane&15 (a), row=(lane>>4)*4+reg (l).
    float s0[4] = {0.f, 0.f, 0.f, 0.f};
    float s1[4] = {0.f, 0.f, 0.f, 0.f};
    #pragma unroll
    for (int ct = 0; ct < 16; ++ct) {
        int a = ct * 16 + r;
        float hba = hb[b * Aa + a];
        float w2a = W2[a];
        #pragma unroll
        for (int reg = 0; reg < 4; ++reg) {
            {
                float pr = acc[0][ct][reg] + hba;
                float e = __expf(2.f * pr);
                float t = (e - 1.f) * __builtin_amdgcn_rcpf(e + 1.f);
                s0[reg] += t * w2a;
            }
            {
                float pr = acc[1][ct][reg] + hba;
                float e = __expf(2.f * pr);
                float t = (e - 1.f) * __builtin_amdgcn_rcpf(e + 1.f);
                s1[reg] += t * w2a;
            }
        }
    }
    // reduce over a: across the 16 lanes of each quarter-wave
    #pragma unroll
    for (int off = 1; off < 16; off <<= 1) {
        #pragma unroll
        for (int reg = 0; reg < 4; ++reg) {
            s0[reg] += __shfl_xor(s0[reg], off, 64);
            s1[reg] += __shfl_xor(s1[reg], off, 64);
        }
    }
    if (r == 0) {
        #pragma unroll
        for (int reg = 0; reg < 4; ++reg) {
            score[rowbase + g * 4 + reg]      = s0[reg];
            score[rowbase + 16 + g * 4 + reg] = s1[reg];
        }
    }
}

// ---------------- k3: masked softmax over L per batch ----------------------
__global__ void k_softmax(const float* __restrict__ score, const int* __restrict__ mask,
                          float* __restrict__ p) {
    __shared__ float smx[4];
    __shared__ float ssm[4];
    int b = blockIdx.x, tid = threadIdx.x;         // 256 threads, 8 vals each
    float v[8]; int mk[8];
    #pragma unroll
    for (int i = 0; i < 8; i++) {
        int l = i * 256 + tid;
        v[i]  = score[b * Ll + l];
        mk[i] = mask[b * Ll + l];
    }
    float mx = -1e30f;
    #pragma unroll
    for (int i = 0; i < 8; i++) if (mk[i]) mx = fmaxf(mx, v[i]);
    for (int off = 1; off < 64; off <<= 1) mx = fmaxf(mx, __shfl_xor(mx, off, 64));
    if ((tid & 63) == 0) smx[tid >> 6] = mx;
    __syncthreads();
    mx = fmaxf(fmaxf(smx[0], smx[1]), fmaxf(smx[2], smx[3]));

    float e[8]; float s = 0.f;
    #pragma unroll
    for (int i = 0; i < 8; i++) { e[i] = mk[i] ? __expf(v[i] - mx) : 0.f; s += e[i]; }
    for (int off = 1; off < 64; off <<= 1) s += __shfl_xor(s, off, 64);
    if ((tid & 63) == 0) ssm[tid >> 6] = s;
    __syncthreads();
    s = ssm[0] + ssm[1] + ssm[2] + ssm[3];
    float inv = 1.f / s;
    #pragma unroll
    for (int i = 0; i < 8; i++) p[b * Ll + i * 256 + tid] = e[i] * inv;
}

// ---------------- k4: expected[b,m] = sum_l p[b,l]*mem[b,l,m] --------------
__global__ void k_expected(const float* __restrict__ mem, const float* __restrict__ p,
                           float* __restrict__ out) {
    int b  = blockIdx.x >> 4;
    int ch = blockIdx.x & 15;                      // 16 chunks of 128 l
    int m4 = (threadIdx.x & 127) << 2;             // float4 over M=512
    int ls = threadIdx.x >> 7;                     // 2 l-substreams
    f32x4 acc = (f32x4){0.f, 0.f, 0.f, 0.f};
    const float* base = mem + (size_t)b * Ll * Mm + (size_t)ch * 128 * Mm;
    const float* pb = p + b * Ll + ch * 128;
    for (int il = ls; il < 128; il += 2) {
        float pv = pb[il];
        f32x4 mv = *reinterpret_cast<const f32x4*>(base + (size_t)il * Mm + m4);
        acc += mv * pv;
    }
    float* o = out + b * Mm + m4;
    atomicAdd(o + 0, acc[0]);
    atomicAdd(o + 1, acc[1]);
    atomicAdd(o + 2, acc[2]);
    atomicAdd(o + 3, acc[3]);
}

extern "C" void kernel_launch(void* const* d_in, const int* in_sizes, int n_in,
                              void* d_out, int out_size, void* d_ws, size_t ws_size,
                              hipStream_t stream) {
    const float* memory = (const float*)d_in[0];
    const float* hidden = (const float*)d_in[1];
    const int*   mask   = (const int*)d_in[2];
    const float* W1     = (const float*)d_in[3];
    const float* b1     = (const float*)d_in[4];
    const float* W2     = (const float*)d_in[5];
    // b2 (d_in[6]) is a constant shift -> cancels in softmax.
    float* out = (float*)d_out;

    // ws layout: [0, 256KB) W1m bf16 | [256KB, 288KB) hb | [288KB, 544KB) score
    unsigned short* W1mb = (unsigned short*)d_ws;
    float* hb    = (float*)((char*)d_ws + 256 * 1024);
    float* score = (float*)((char*)d_ws + 256 * 1024 + 32 * 1024);
    float* p = out + Bb * Mm;                      // p_memory region of d_out

    hipMemsetAsync(out, 0, (size_t)Bb * Mm * sizeof(float), stream);   // expected accum
    hipMemsetAsync(hb, 0, (size_t)Bb * Aa * sizeof(float), stream);

    k_convert_w1m<<<128, 256, 0, stream>>>(W1, W1mb);
    k_hb<<<128, 256, 0, stream>>>(hidden, W1, b1, hb);
    k_score<<<512, 256, 0, stream>>>(memory, W1mb, hb, W2, score);
    k_softmax<<<32, 256, 0, stream>>>(score, mask, p);
    k_expected<<<512, 256, 0, stream>>>(memory, p, out);
}

// Round 3
// 244.190 us; speedup vs baseline: 1.1880x; 1.1880x over previous
//
#include <hip/hip_runtime.h>
#include <hip/hip_bf16.h>

// Sizes fixed by the problem
constexpr int Bb = 32;
constexpr int Ll = 2048;
constexpr int Mm = 512;
constexpr int Hh = 512;
constexpr int Aa = 256;

typedef __attribute__((ext_vector_type(4))) float f32x4;
typedef __attribute__((ext_vector_type(8))) short short8;
typedef __attribute__((ext_vector_type(4))) unsigned short ushort4v;

__device__ __forceinline__ unsigned short f2bf(float f) {
    __hip_bfloat16 h = __float2bfloat16(f);   // RNE
    return *reinterpret_cast<unsigned short*>(&h);
}

__device__ __forceinline__ ushort4v cvt4(f32x4 v) {
    ushort4v o;
    o[0] = f2bf(v[0]); o[1] = f2bf(v[1]); o[2] = f2bf(v[2]); o[3] = f2bf(v[3]);
    return o;
}

// async global->LDS, 16B per lane; lds dest must be wave-uniform base (+lane*16 by HW)
__device__ __forceinline__ void gload_lds16(const void* g, void* l) {
    __builtin_amdgcn_global_load_lds(
        (const __attribute__((address_space(1))) unsigned int*)g,
        (__attribute__((address_space(3))) unsigned int*)l, 16, 0, 0);
}

// ---------------- k0: W1[:, :512] -> bf16, PERMUTED [ks][a][32] ------------
// so that k_score's per-K-step B tile (16KB) is one contiguous chunk.
__global__ void k_convert_w1m(const float* __restrict__ W1,
                              unsigned short* __restrict__ W1mb) {
    int i = blockIdx.x * 256 + threadIdx.x;        // 32768 threads, 4 floats each
    int a  = i >> 7;                               // 128 float4 per row
    int mq = (i & 127) << 2;
    f32x4 v = *reinterpret_cast<const f32x4*>(W1 + (size_t)a * (Mm + Hh) + mq);
    int ks = mq >> 5;                              // K-step index (32 k per step)
    int kb = mq & 31;
    *reinterpret_cast<ushort4v*>(W1mb + (size_t)ks * (Aa * 32) + a * 32 + kb) = cvt4(v);
}

// ---------------- k1: hb[b][a] = sum_h hidden[b,h]*W1[a,512+h] + b1[a] -----
__global__ void k_hb(const float* __restrict__ hidden, const float* __restrict__ W1,
                     const float* __restrict__ b1, float* __restrict__ hb) {
    int b  = blockIdx.x >> 2;
    int hc = blockIdx.x & 3;                       // 4 chunks of 128 h
    int a  = threadIdx.x;                          // 256 threads
    __shared__ float sh[128];
    if (threadIdx.x < 128) sh[threadIdx.x] = hidden[b * Hh + hc * 128 + threadIdx.x];
    __syncthreads();
    const float* wrow = W1 + (size_t)a * (Mm + Hh) + Mm + hc * 128;
    float acc = (hc == 0) ? b1[a] : 0.f;
    #pragma unroll 8
    for (int h = 0; h < 128; h += 4) {
        f32x4 w = *reinterpret_cast<const f32x4*>(wrow + h);
        acc += w[0] * sh[h] + w[1] * sh[h + 1] + w[2] * sh[h + 2] + w[3] * sh[h + 3];
    }
    atomicAdd(&hb[b * Aa + a], acc);
}

// ---------------- k2: fused score GEMM (m97-style LDS double buffer) -------
// score[b,l] = sum_a tanh( mem[b,l,:].W1m[a,:] + hb[b,a] ) * W2[a]
// Grid 1024 blocks x 256 thr (4 waves). Block tile BM=64 rows, BN=256, BK=32.
// Wave w owns rows [w*16, w*16+16) x all 256 cols: acc[16] f32x4 = 64 regs.
__launch_bounds__(256, 4)
__global__ void k_score(const float* __restrict__ mem,
                        const unsigned short* __restrict__ W1mb,
                        const float* __restrict__ hb, const float* __restrict__ W2,
                        float* __restrict__ score) {
    __shared__ unsigned short ldsA[2][64 * 32];    // 4KB each: [row][k] bf16
    __shared__ unsigned short ldsB[2][256 * 32];   // 16KB each: [a][k] bf16

    const int tid  = threadIdx.x;
    const int wave = tid >> 6;
    const int lane = tid & 63;
    const int g = lane >> 4;                       // k-group 0..3
    const int r = lane & 15;                       // own-dim index
    const int blockRow = blockIdx.x * 64;
    const int b = blockRow >> 11;                  // 2048 rows per batch

    f32x4 acc[16];
    #pragma unroll
    for (int ct = 0; ct < 16; ct++) acc[ct] = (f32x4){0.f, 0.f, 0.f, 0.f};

    // A staging: 64 rows x 32 fp32 = 512 chunks of 16B; thread handles c0,c1
    const int c0 = tid, c1 = tid + 256;
    const float* gA0 = mem + (size_t)(blockRow + (c0 >> 3)) * Mm + (c0 & 7) * 4;
    const float* gA1 = mem + (size_t)(blockRow + (c1 >> 3)) * Mm + (c1 & 7) * 4;
    const char* gB = (const char*)W1mb;            // permuted: step ks at byte ks*16384

    // prologue: stage ks=0 into buf 0
    {
        #pragma unroll
        for (int j = 0; j < 4; ++j)
            gload_lds16(gB + (size_t)(wave * 4 + j) * 1024 + lane * 16,
                        &ldsB[0][(wave * 4 + j) * 512]);
        f32x4 a0 = *reinterpret_cast<const f32x4*>(gA0);
        f32x4 a1 = *reinterpret_cast<const f32x4*>(gA1);
        *reinterpret_cast<ushort4v*>(&ldsA[0][c0 * 4]) = cvt4(a0);
        *reinterpret_cast<ushort4v*>(&ldsA[0][c1 * 4]) = cvt4(a1);
    }
    __syncthreads();

    for (int ks = 0; ks < 16; ++ks) {
        const int cur = ks & 1, nxt = cur ^ 1;
        f32x4 a0, a1;
        if (ks < 15) {
            const int ko = (ks + 1) * 32;
            #pragma unroll
            for (int j = 0; j < 4; ++j)
                gload_lds16(gB + (size_t)(ks + 1) * 16384 + (wave * 4 + j) * 1024 + lane * 16,
                            &ldsB[nxt][(wave * 4 + j) * 512]);
            a0 = *reinterpret_cast<const f32x4*>(gA0 + ko);
            a1 = *reinterpret_cast<const f32x4*>(gA1 + ko);
        }
        // compute current tile
        short8 af = *reinterpret_cast<const short8*>(&ldsA[cur][(wave * 16 + r) * 32 + g * 8]);
        #pragma unroll
        for (int h = 0; h < 4; ++h) {
            short8 bf[4];
            #pragma unroll
            for (int j = 0; j < 4; ++j)
                bf[j] = *reinterpret_cast<const short8*>(&ldsB[cur][((h * 4 + j) * 16 + r) * 32 + g * 8]);
            #pragma unroll
            for (int j = 0; j < 4; ++j)
                acc[h * 4 + j] = __builtin_amdgcn_mfma_f32_16x16x32_bf16(af, bf[j], acc[h * 4 + j], 0, 0, 0);
        }
        if (ks < 15) {
            *reinterpret_cast<ushort4v*>(&ldsA[nxt][c0 * 4]) = cvt4(a0);
            *reinterpret_cast<ushort4v*>(&ldsA[nxt][c1 * 4]) = cvt4(a1);
        }
        __syncthreads();
    }

    // Epilogue: C/D layout col=lane&15 (a), row=(lane>>4)*4+reg (l within tile)
    float s[4] = {0.f, 0.f, 0.f, 0.f};
    #pragma unroll
    for (int ct = 0; ct < 16; ++ct) {
        int a = ct * 16 + r;
        float hba = hb[b * Aa + a];
        float w2a = W2[a];
        #pragma unroll
        for (int reg = 0; reg < 4; ++reg) {
            float pr = acc[ct][reg] + hba;
            float e = __expf(2.f * pr);
            float t = (e - 1.f) * __builtin_amdgcn_rcpf(e + 1.f);
            s[reg] += t * w2a;
        }
    }
    #pragma unroll
    for (int off = 1; off < 16; off <<= 1) {
        #pragma unroll
        for (int reg = 0; reg < 4; ++reg) s[reg] += __shfl_xor(s[reg], off, 64);
    }
    if (r == 0) {
        #pragma unroll
        for (int reg = 0; reg < 4; ++reg)
            score[blockRow + wave * 16 + g * 4 + reg] = s[reg];
    }
}

// ---------------- k3: masked softmax over L per batch ----------------------
__global__ void k_softmax(const float* __restrict__ score, const int* __restrict__ mask,
                          float* __restrict__ p) {
    __shared__ float smx[4];
    __shared__ float ssm[4];
    int b = blockIdx.x, tid = threadIdx.x;         // 256 threads, 8 vals each
    float v[8]; int mk[8];
    #pragma unroll
    for (int i = 0; i < 8; i++) {
        int l = i * 256 + tid;
        v[i]  = score[b * Ll + l];
        mk[i] = mask[b * Ll + l];
    }
    float mx = -1e30f;
    #pragma unroll
    for (int i = 0; i < 8; i++) if (mk[i]) mx = fmaxf(mx, v[i]);
    for (int off = 1; off < 64; off <<= 1) mx = fmaxf(mx, __shfl_xor(mx, off, 64));
    if ((tid & 63) == 0) smx[tid >> 6] = mx;
    __syncthreads();
    mx = fmaxf(fmaxf(smx[0], smx[1]), fmaxf(smx[2], smx[3]));

    float e[8]; float s = 0.f;
    #pragma unroll
    for (int i = 0; i < 8; i++) { e[i] = mk[i] ? __expf(v[i] - mx) : 0.f; s += e[i]; }
    for (int off = 1; off < 64; off <<= 1) s += __shfl_xor(s, off, 64);
    if ((tid & 63) == 0) ssm[tid >> 6] = s;
    __syncthreads();
    s = ssm[0] + ssm[1] + ssm[2] + ssm[3];
    float inv = 1.f / s;
    #pragma unroll
    for (int i = 0; i < 8; i++) p[b * Ll + i * 256 + tid] = e[i] * inv;
}

// ---------------- k4: expected[b,m] = sum_l p[b,l]*mem[b,l,m] --------------
// Atomic-free: 512 blocks = 32 b x 16 m-chunks of 32 m; 32 l-streams/block.
__global__ void k_expected(const float* __restrict__ mem, const float* __restrict__ p,
                           float* __restrict__ out) {
    __shared__ f32x4 sred[32][8];
    int b  = blockIdx.x >> 4;
    int mc = blockIdx.x & 15;                      // 32 m per chunk
    int mi = threadIdx.x & 7;                      // float4 index within chunk
    int ls = threadIdx.x >> 3;                     // 32 l-streams
    const float* base = mem + (size_t)b * Ll * Mm + mc * 32 + mi * 4;
    const float* pb = p + b * Ll;
    f32x4 acc = (f32x4){0.f, 0.f, 0.f, 0.f};
    for (int il = ls; il < Ll; il += 32) {
        float pv = pb[il];
        f32x4 mv = *reinterpret_cast<const f32x4*>(base + (size_t)il * Mm);
        acc += mv * pv;
    }
    sred[ls][mi] = acc;
    __syncthreads();
    #pragma unroll
    for (int s = 16; s > 0; s >>= 1) {
        if (ls < s) sred[ls][mi] += sred[ls + s][mi];
        __syncthreads();
    }
    if (ls == 0)
        *reinterpret_cast<f32x4*>(out + b * Mm + mc * 32 + mi * 4) = sred[0][mi];
}

extern "C" void kernel_launch(void* const* d_in, const int* in_sizes, int n_in,
                              void* d_out, int out_size, void* d_ws, size_t ws_size,
                              hipStream_t stream) {
    const float* memory = (const float*)d_in[0];
    const float* hidden = (const float*)d_in[1];
    const int*   mask   = (const int*)d_in[2];
    const float* W1     = (const float*)d_in[3];
    const float* b1     = (const float*)d_in[4];
    const float* W2     = (const float*)d_in[5];
    // b2 (d_in[6]) is a constant shift -> cancels in softmax.
    float* out = (float*)d_out;

    // ws layout: [0, 256KB) W1m bf16 (permuted) | [256KB, 288KB) hb | [288KB, 544KB) score
    unsigned short* W1mb = (unsigned short*)d_ws;
    float* hb    = (float*)((char*)d_ws + 256 * 1024);
    float* score = (float*)((char*)d_ws + 256 * 1024 + 32 * 1024);
    float* p = out + Bb * Mm;                      // p_memory region of d_out

    hipMemsetAsync(hb, 0, (size_t)Bb * Aa * sizeof(float), stream);

    k_convert_w1m<<<128, 256, 0, stream>>>(W1, W1mb);
    k_hb<<<128, 256, 0, stream>>>(hidden, W1, b1, hb);
    k_score<<<1024, 256, 0, stream>>>(memory, W1mb, hb, W2, score);
    k_softmax<<<32, 256, 0, stream>>>(score, mask, p);
    k_expected<<<512, 256, 0, stream>>>(memory, p, out);
}